// Round 4
// baseline (89.893 us; speedup 1.0000x reference)
//
#include <hip/hip_runtime.h>

#define NCLS 16
#define DECAY 0.8f

// ---------------------------------------------------------------------------
// Kernel 1: 16-bin histogram. int4 loads, 4 LDS sub-histograms (one per wave)
// to cut same-address atomic contention 4x.
// ---------------------------------------------------------------------------
__global__ void dwce_hist_kernel(const int4* __restrict__ targets4,
                                 unsigned int* __restrict__ counts, int n4) {
    __shared__ unsigned int lhist[4 * NCLS];
    const int tid = threadIdx.x;
    if (tid < 4 * NCLS) lhist[tid] = 0u;
    __syncthreads();

    const int wid = tid >> 6;                 // wave id 0..3
    unsigned int* h = &lhist[wid << 4];
    const int stride = gridDim.x * blockDim.x;
    for (int i = blockIdx.x * blockDim.x + tid; i < n4; i += stride) {
        int4 t = targets4[i];
        atomicAdd(&h[t.x], 1u);
        atomicAdd(&h[t.y], 1u);
        atomicAdd(&h[t.z], 1u);
        atomicAdd(&h[t.w], 1u);
    }
    __syncthreads();
    if (tid < 4 * NCLS) atomicAdd(&counts[tid & (NCLS - 1)], lhist[tid]);
}

// select element t (0..15) from a row held as 4 float4s — pure cndmask chain
__device__ __forceinline__ float sel16(float4 q0, float4 q1, float4 q2,
                                       float4 q3, int t) {
    float4 sv = (t & 8) ? ((t & 4) ? q3 : q2) : ((t & 4) ? q1 : q0);
    const float lo = (t & 1) ? sv.y : sv.x;
    const float hi = (t & 1) ? sv.w : sv.z;
    return (t & 2) ? hi : lo;
}

__device__ __forceinline__ float esum4(float4 v) {
    return __expf(v.x) + __expf(v.y) + __expf(v.z) + __expf(v.w);
}

// ---------------------------------------------------------------------------
// Kernel 2: weighted CE partial sums.
//   - parallel w-preamble: lanes 0..15 (one divide each + shfl_xor sum)
//   - 4 rows / iteration, 2 iterations / thread (grid 1024x256)
//   - fp32 wave+block reduction, float2 partial per block (no atomics)
// ---------------------------------------------------------------------------
__global__ void __launch_bounds__(256, 4)
dwce_main_kernel(const float4* __restrict__ logits4,
                 const int4*   __restrict__ targets4,
                 const float*  __restrict__ weight,
                 const unsigned int* __restrict__ counts,
                 float2* __restrict__ partials, int n) {
    __shared__ float w[NCLS];
    const int tid = threadIdx.x;
    if (tid < NCLS) {
        const float raw = (float)n / (float)counts[tid];
        float s = raw;
        s += __shfl_xor(s, 1);
        s += __shfl_xor(s, 2);
        s += __shfl_xor(s, 4);
        s += __shfl_xor(s, 8);
        w[tid] = DECAY * weight[tid] + (1.0f - DECAY) * (raw / s);
    }
    __syncthreads();

    const int gid  = blockIdx.x * blockDim.x + tid;
    const int nth  = gridDim.x * blockDim.x;
    const int ngrp = n >> 2;   // groups of 4 rows

    float accA = 0.f;   // sum(w[t] * nll)
    float accB = 0.f;   // sum(w[t])

    for (int g = gid; g < ngrp; g += nth) {
        const int4 t = targets4[g];                       // 4 targets, one load
        const float4* base = logits4 + ((size_t)g << 4);  // 4 rows = 16 float4
        float4 a0 = base[0],  a1 = base[1],  a2 = base[2],  a3 = base[3];
        float4 b0 = base[4],  b1 = base[5],  b2 = base[6],  b3 = base[7];
        float4 c0 = base[8],  c1 = base[9],  c2 = base[10], c3 = base[11];
        float4 d0 = base[12], d1 = base[13], d2 = base[14], d3 = base[15];

        const float S0 = esum4(a0) + esum4(a1) + esum4(a2) + esum4(a3);
        const float S1 = esum4(b0) + esum4(b1) + esum4(b2) + esum4(b3);
        const float S2 = esum4(c0) + esum4(c1) + esum4(c2) + esum4(c3);
        const float S3 = esum4(d0) + esum4(d1) + esum4(d2) + esum4(d3);

        const float x0 = sel16(a0, a1, a2, a3, t.x);
        const float x1 = sel16(b0, b1, b2, b3, t.y);
        const float x2 = sel16(c0, c1, c2, c3, t.z);
        const float x3 = sel16(d0, d1, d2, d3, t.w);

        const float w0 = w[t.x], w1 = w[t.y], w2 = w[t.z], w3 = w[t.w];
        accA += w0 * (__logf(S0) - x0) + w1 * (__logf(S1) - x1) +
                w2 * (__logf(S2) - x2) + w3 * (__logf(S3) - x3);
        accB += (w0 + w1) + (w2 + w3);
    }

    // fp32 wave reduce (1 bpermute per shuffle), then block reduce
    #pragma unroll
    for (int off = 32; off > 0; off >>= 1) {
        accA += __shfl_down(accA, off);
        accB += __shfl_down(accB, off);
    }
    __shared__ float sA[4], sB[4];  // 4 waves
    const int wid  = tid >> 6;
    const int lane = tid & 63;
    if (lane == 0) { sA[wid] = accA; sB[wid] = accB; }
    __syncthreads();
    if (tid == 0) {
        partials[blockIdx.x] =
            make_float2(sA[0] + sA[1] + sA[2] + sA[3],
                        sB[0] + sB[1] + sB[2] + sB[3]);
    }
}

// ---------------------------------------------------------------------------
// Kernel 3: reduce per-block partials in double, finalize scalar.
// ---------------------------------------------------------------------------
__global__ void dwce_final_kernel(const float2* __restrict__ partials, int nb,
                                  float* __restrict__ out) {
    double a = 0.0, b = 0.0;
    for (int i = threadIdx.x; i < nb; i += blockDim.x) {
        const float2 p = partials[i];
        a += (double)p.x;
        b += (double)p.y;
    }
    #pragma unroll
    for (int off = 32; off > 0; off >>= 1) {
        a += __shfl_down(a, off);
        b += __shfl_down(b, off);
    }
    __shared__ double sA[4], sB[4];
    const int wid  = threadIdx.x >> 6;
    const int lane = threadIdx.x & 63;
    if (lane == 0) { sA[wid] = a; sB[wid] = b; }
    __syncthreads();
    if (threadIdx.x == 0) {
        out[0] = (float)((sA[0] + sA[1] + sA[2] + sA[3]) /
                         (sB[0] + sB[1] + sB[2] + sB[3]));
    }
}

extern "C" void kernel_launch(void* const* d_in, const int* in_sizes, int n_in,
                              void* d_out, int out_size, void* d_ws, size_t ws_size,
                              hipStream_t stream) {
    const float* logits  = (const float*)d_in[0];
    const int*   targets = (const int*)d_in[1];
    const float* weight  = (const float*)d_in[2];
    float* out = (float*)d_out;

    unsigned int* counts   = (unsigned int*)d_ws;            // 64 B
    float2*       partials = (float2*)((char*)d_ws + 256);   // nb * 8 B

    const int n = in_sizes[1];  // N samples

    int nb = 1024;
    const int ws_cap = (int)((ws_size > 256 ? ws_size - 256 : 0) / sizeof(float2));
    if (nb > ws_cap) nb = ws_cap;
    if (nb < 1) nb = 1;

    // d_ws poisoned 0xAA once, never re-poisoned -> zero counts each call.
    hipMemsetAsync(d_ws, 0, 64, stream);

    dwce_hist_kernel<<<256, 256, 0, stream>>>((const int4*)targets, counts, n / 4);
    dwce_main_kernel<<<nb, 256, 0, stream>>>((const float4*)logits,
                                             (const int4*)targets, weight,
                                             counts, partials, n);
    dwce_final_kernel<<<1, 256, 0, stream>>>(partials, nb, out);
}